// Round 3
// baseline (350.524 us; speedup 1.0000x reference)
//
#include <hip/hip_runtime.h>
#include <hip/hip_bf16.h>

// PackedAvgPool1d: out[t, :] = mean(x[gather_base[t] + i, :] for i < min(rem[t], K))
// K = 2, S = 2, D = 768.
//
// Dtype model (established by rounds 1-2 error forensics): ALL fp32, exactly
// as the reference declares. The harness "(bf16, ...)" label is a hardcoded
// string, not a dtype probe.
//  - H(bf16 in, bf16 out): round-1 kernel == this, failed 5.69 -> rejected.
//  - H(bf16 in, fp32 out): round-2 kernel == this, failed NaN -> rejected.
//  - H(fp32 in, bf16 out): round 1 would show ~1e38/NaN, not 5.69 -> rejected.
//  - H(fp32 in, fp32 out): round-1 5.69 (sane-but-misplaced values, exponent
//    from odd bf16 halves) and round-2 NaN (fp32 halves decoded as bf16 hit
//    exp=0xFF patterns) both predicted exactly. -> confirmed.
//
// Memory-bound: ~226 MB fp32 read + ~113 MB fp32 write ~= 340 MB -> ~54 us
// roofline at 6.3 TB/s achievable.

namespace {

constexpr int kD = 768;             // feature dim
constexpr int kVec = 4;             // 4 floats/thread: 16B load + 16B store
constexpr int kChunks = kD / kVec;  // 192 chunks per row
constexpr int kBlock = 256;

__global__ __launch_bounds__(kBlock)
void packed_avgpool1d_kernel(const float* __restrict__ x,
                             const int* __restrict__ gbase,
                             const int* __restrict__ rem,
                             const int* __restrict__ kptr,
                             float* __restrict__ out,
                             int n_chunks_total) {
  const int t = blockIdx.x * kBlock + threadIdx.x;
  if (t >= n_chunks_total) return;

  const int K = kptr[0];                 // runtime scalar (always 2 here)
  const int row = t / kChunks;           // const divide -> magic-mul
  const int c = t - row * kChunks;

  const int base = gbase[row];
  const int cnt = min(rem[row], K);      // cnt in {1, 2}; rem >= 1 guaranteed

  float acc[kVec];
#pragma unroll
  for (int e = 0; e < kVec; ++e) acc[e] = 0.0f;

  // Guard each row-load behind i < cnt: when rem==1 the next row can be
  // one-past-end of x (last window of last sequence) -> must not load it.
  const float* p = x + (size_t)base * kD + (size_t)c * kVec;
  for (int i = 0; i < cnt; ++i) {
    float4 v = *reinterpret_cast<const float4*>(p + (size_t)i * kD);
    acc[0] += v.x;
    acc[1] += v.y;
    acc[2] += v.z;
    acc[3] += v.w;
  }

  const float scale = 1.0f / (float)cnt;
  float4 o;
  o.x = acc[0] * scale;
  o.y = acc[1] * scale;
  o.z = acc[2] * scale;
  o.w = acc[3] * scale;
  *reinterpret_cast<float4*>(out + (size_t)row * kD + (size_t)c * kVec) = o;
}

}  // namespace

extern "C" void kernel_launch(void* const* d_in, const int* in_sizes, int n_in,
                              void* d_out, int out_size, void* d_ws, size_t ws_size,
                              hipStream_t stream) {
  const float* x = (const float*)d_in[0];        // [Tx, 768] fp32
  const int* gbase = (const int*)d_in[1];        // [Ty]
  const int* rem = (const int*)d_in[2];          // [Ty]
  const int* kptr = (const int*)d_in[3];         // scalar K
  float* out = (float*)d_out;                    // [Ty, 768] fp32

  const int Ty = in_sizes[1];
  const int total = Ty * kChunks;
  const int blocks = (total + kBlock - 1) / kBlock;

  hipLaunchKernelGGL(packed_avgpool1d_kernel, dim3(blocks), dim3(kBlock), 0,
                     stream, x, gbase, rem, kptr, out, total);
}

// Round 5
// 350.221 us; speedup vs baseline: 1.0009x; 1.0009x over previous
//
#include <hip/hip_runtime.h>
#include <hip/hip_bf16.h>

// PackedAvgPool1d: out[t, :] = mean(x[gather_base[t] + i, :] for i < min(rem[t], K))
// K = 2, S = 2, D = 768. All fp32 (confirmed round 3: passed, absmax == 0.0).
//
// Memory-bound: 226 MB fp32 read + 113 MB fp32 write = 340 MB -> ~54 us floor
// at 6.3 TB/s. Bench dur_us (~350 in R3) folds in per-iteration harness
// resets (944 MB poison fills at 6.6 TB/s visible in rocprof) — our dispatch
// is < 142 us (absent from dur-sorted top-5).
//
// R5 = R4 fixed: __builtin_nontemporal_store needs a NATIVE clang vector
// (ext_vector_type), not HIP's float4 class — that was a compile error only.
// R4 theory unchanged: branchless K==2 fast path. rem >= 1 always; when
// cnt == 1 the second-row pointer is clamped onto the first row, so v1 == v0
// and (v0 + v1) * 0.5 == v0 EXACTLY; cnt == 2: *0.5 == /2 exactly. Both
// loads issue with no loop-carried dependency (2x MLP vs runtime loop).
// Nontemporal store for out (stream-once, keep L2 for x).

namespace {

typedef float vfloat4 __attribute__((ext_vector_type(4)));  // native vec4

constexpr int kD = 768;             // feature dim
constexpr int kVec = 4;             // 4 floats/thread: 16B load + 16B store
constexpr int kChunks = kD / kVec;  // 192 chunks per row
constexpr int kBlock = 256;

__global__ __launch_bounds__(kBlock)
void packed_avgpool1d_kernel(const float* __restrict__ x,
                             const int* __restrict__ gbase,
                             const int* __restrict__ rem,
                             const int* __restrict__ kptr,
                             float* __restrict__ out,
                             int n_chunks_total) {
  const int t = blockIdx.x * kBlock + threadIdx.x;
  if (t >= n_chunks_total) return;

  const int K = kptr[0];                 // runtime scalar (always 2 here)
  const int row = t / kChunks;           // const divide -> magic-mul
  const int c = t - row * kChunks;

  const int base = gbase[row];
  const int cnt = min(rem[row], K);      // cnt in {1, 2}; rem >= 1 guaranteed

  const float* p = x + (size_t)base * kD + (size_t)c * kVec;
  float* po = out + (size_t)row * kD + (size_t)c * kVec;

  if (K == 2) {                          // wave-uniform; always taken here
    // Clamp second-row ptr into row 0 when cnt==1 -> always in-bounds, and
    // v1 == v0 makes the averaging formula exact for both cnt values.
    const float* p1 = p + (cnt > 1 ? kD : 0);
    const vfloat4 v0 = *reinterpret_cast<const vfloat4*>(p);
    const vfloat4 v1 = *reinterpret_cast<const vfloat4*>(p1);
    const vfloat4 o = (v0 + v1) * 0.5f;
    __builtin_nontemporal_store(o, reinterpret_cast<vfloat4*>(po));
  } else {                               // generic fallback (never hit: K==2)
    vfloat4 acc = {0.0f, 0.0f, 0.0f, 0.0f};
    for (int i = 0; i < cnt; ++i)
      acc += *reinterpret_cast<const vfloat4*>(p + (size_t)i * kD);
    const vfloat4 o = acc * (1.0f / (float)cnt);
    __builtin_nontemporal_store(o, reinterpret_cast<vfloat4*>(po));
  }
}

}  // namespace

extern "C" void kernel_launch(void* const* d_in, const int* in_sizes, int n_in,
                              void* d_out, int out_size, void* d_ws, size_t ws_size,
                              hipStream_t stream) {
  const float* x = (const float*)d_in[0];        // [Tx, 768] fp32
  const int* gbase = (const int*)d_in[1];        // [Ty]
  const int* rem = (const int*)d_in[2];          // [Ty]
  const int* kptr = (const int*)d_in[3];         // scalar K
  float* out = (float*)d_out;                    // [Ty, 768] fp32

  const int Ty = in_sizes[1];
  const int total = Ty * kChunks;
  const int blocks = (total + kBlock - 1) / kBlock;

  hipLaunchKernelGGL(packed_avgpool1d_kernel, dim3(blocks), dim3(kBlock), 0,
                     stream, x, gbase, rem, kptr, out, total);
}